// Round 2
// baseline (239.927 us; speedup 1.0000x reference)
//
#include <hip/hip_runtime.h>

// Problem constants (from reference)
#define B_   8192
#define NY_  8
#define MT_  32
#define RR_  16
constexpr float PAR_WIDTH  = 0.6f;
constexpr float MAX_LENGTH = 5.0f;

// Flat element counts
constexpr long N_SLOT  = (long)B_ * NY_ * MT_ * RR_ * 2;  // 67,108,864
constexpr long N_LW    = (long)B_ * NY_ * MT_ * RR_;      // 33,554,432
constexpr long N_CNT   = (long)B_ * NY_;                  // 65,536

// Output offsets (elements) in the concatenated d_out (all float32)
constexpr long OFF_SLOT = 0;
constexpr long OFF_LEN  = N_SLOT;
constexpr long OFF_WID  = N_SLOT + N_LW;
constexpr long OFF_CNT  = N_SLOT + 2 * N_LW;

// float4 counts per region
constexpr long S1 = N_SLOT / 4;        // slot region end   (16,777,216)
constexpr long S2 = S1 + N_LW / 4;     // len region end    (+8,388,608)
constexpr long S3 = S2 + N_LW / 4;     // wid region end    (+8,388,608)

// One fused streaming pass over slot+len+wid: int4->float4 convert for the
// slot region, straight float4 copy for len/wid. One kernel = one ramp, no
// inter-kernel gaps.
__global__ void fused_copy(const int*   __restrict__ slot_in,
                           const float* __restrict__ lens,
                           const float* __restrict__ wids,
                           float* __restrict__ out) {
    long i = (long)blockIdx.x * blockDim.x + threadIdx.x;
    const long stride = (long)gridDim.x * blockDim.x;
    const int4*   in_s = reinterpret_cast<const int4*>(slot_in);
    const float4* in_l = reinterpret_cast<const float4*>(lens);
    const float4* in_w = reinterpret_cast<const float4*>(wids);
    float4* o = reinterpret_cast<float4*>(out);
    for (; i < S3; i += stride) {
        if (i < S1) {
            int4 v = in_s[i];
            float4 f;
            f.x = (float)v.x; f.y = (float)v.y; f.z = (float)v.z; f.w = (float)v.w;
            o[i] = f;
        } else if (i < S2) {
            o[i] = in_l[i - S1];
        } else {
            o[i] = in_w[i - S2];
        }
    }
}

// One thread per batch element: convert+copy its barge_count row, then apply
// the sparse update logic on top of the already-copied outputs.
__global__ void update_kernel(const int*   __restrict__ sel,      // [B]
                              const float* __restrict__ bsz,      // [B,1,5]
                              const int*   __restrict__ ysel,     // [B]
                              const int*   __restrict__ bcnt,     // [B,NY]
                              const float* __restrict__ lens,     // [B,NY,MT,RR]
                              const float* __restrict__ wids,     // [B,NY,MT,RR]
                              float* __restrict__ out) {
    int b = blockIdx.x * blockDim.x + threadIdx.x;
    if (b >= B_) return;

    float* out_slot = out + OFF_SLOT;
    float* out_len  = out + OFF_LEN;
    float* out_wid  = out + OFF_WID;
    float* out_cnt  = out + OFF_CNT;

    // copy/convert this b's barge_count row
    #pragma unroll
    for (int j = 0; j < NY_; ++j)
        out_cnt[(long)b * NY_ + j] = (float)bcnt[(long)b * NY_ + j];

    const int y = ysel[b];
    const int s = bcnt[(long)b * NY_ + y];

    const long base = ((((long)b * NY_ + y) * MT_) + s) * RR_;
    const float blen = bsz[(long)b * 5 + 0];
    const float bwid = bsz[(long)b * 5 + 1];

    bool has_par_space = false;
    bool has_valid     = false;
    float maxv = -1e30f;
    int   maxi = 0;
    float total = 0.0f;

    #pragma unroll
    for (int r = 0; r < RR_; ++r) {
        const float wr = wids[base + r];
        const float lr = lens[base + r];
        const bool par = (wr <= PAR_WIDTH);
        has_par_space |= par;
        has_valid     |= (par && (wr != 0.0f));
        const float pl = par ? lr : -1.0f;
        if (pl > maxv) { maxv = pl; maxi = r; }  // first-max (strict >)
        total += lr;
    }

    const bool is_par_block = (bwid <= PAR_WIDTH);
    const bool par_alloc    = is_par_block && has_par_space;
    const bool has_existing = has_valid && par_alloc;

    const bool dir_mask  = has_existing && (maxv >= blen);
    const bool recons    = has_existing && (maxv <  blen);
    const bool allocable = (total - maxv + blen) <= MAX_LENGTH;
    const bool ra  = recons && allocable;
    const bool rna = recons && !allocable;

    if (dir_mask || ra) {
        out_slot[(base + maxi) * 2 + 1] = (float)sel[b];
        out_wid[base + maxi] = wids[base + maxi] + bwid;
        if (ra) out_len[base + maxi] = blen;
    }
    if (rna) {
        out_cnt[(long)b * NY_ + y] = (float)(s + 1);
        const int s2 = min(s + 1, MT_ - 1);
        const long base2 = ((((long)b * NY_ + y) * MT_) + s2) * RR_;
        out_slot[base2 * 2 + 0] = (float)sel[b];
        out_len[base2] = blen;
        out_wid[base2] = wids[base2] + bwid;
    }
}

extern "C" void kernel_launch(void* const* d_in, const int* in_sizes, int n_in,
                              void* d_out, int out_size, void* d_ws, size_t ws_size,
                              hipStream_t stream) {
    const int*   block_selection = (const int*)  d_in[0];
    const float* block_size      = (const float*)d_in[1];
    const int*   yard_selection  = (const int*)  d_in[2];
    const int*   barge_count     = (const int*)  d_in[3];
    const int*   barge_slot      = (const int*)  d_in[4];
    const float* lens            = (const float*)d_in[5];
    const float* wids            = (const float*)d_in[6];
    float* out = (float*)d_out;

    // One big streaming pass: 33,554,432 float4s. 4096 blocks x 256 threads
    // -> 1M threads, 32 grid-stride iters each (8 resident waves/CU worth of
    // work granularity for tail balance).
    fused_copy<<<4096, 256, 0, stream>>>(barge_slot, lens, wids, out);

    // Sparse updates (+ barge_count convert/copy), ordered after the copy
    update_kernel<<<(B_ + 255) / 256, 256, 0, stream>>>(
        block_selection, block_size, yard_selection, barge_count, lens, wids, out);
}

// Round 4
// 230.994 us; speedup vs baseline: 1.0387x; 1.0387x over previous
//
#include <hip/hip_runtime.h>

// Problem constants (from reference)
#define B_   8192
#define NY_  8
#define MT_  32
#define RR_  16
constexpr float PAR_WIDTH  = 0.6f;
constexpr float MAX_LENGTH = 5.0f;

// Flat element counts
constexpr long N_SLOT  = (long)B_ * NY_ * MT_ * RR_ * 2;  // 67,108,864
constexpr long N_LW    = (long)B_ * NY_ * MT_ * RR_;      // 33,554,432

// Output offsets (elements) in the concatenated d_out (all float32)
constexpr long OFF_SLOT = 0;
constexpr long OFF_LEN  = N_SLOT;
constexpr long OFF_WID  = N_SLOT + N_LW;
constexpr long OFF_CNT  = N_SLOT + 2 * N_LW;

// clang ext vector types — accepted by __builtin_nontemporal_load/store
typedef float fx4 __attribute__((ext_vector_type(4)));
typedef int   ix4 __attribute__((ext_vector_type(4)));

// Block-partitioned single-launch copy.
//   blocks [0, 1024)        : slot region, ix4 -> fx4 convert, 16,777,216 f4
//   blocks [1024, 1536)     : len region, straight copy,        8,388,608 f4
//   blocks [1536, 2048)     : wid region, straight copy,        8,388,608 f4
// Each region: trip count exactly 64 f4/thread, branch-free unrolled body.
constexpr int BLK_SLOT = 1024;
constexpr int BLK_LW   = 512;
constexpr int TPB      = 256;
constexpr int ITERS    = 64;  // 16,777,216/(1024*256) == 8,388,608/(512*256) == 64

__global__ __launch_bounds__(TPB) void copy_part(const int*   __restrict__ slot_in,
                                                 const float* __restrict__ lens,
                                                 const float* __restrict__ wids,
                                                 float* __restrict__ out) {
    const int bid = blockIdx.x;
    if (bid < BLK_SLOT) {
        // slot region: int4 -> float4 convert
        const ix4* in = reinterpret_cast<const ix4*>(slot_in);
        fx4* o = reinterpret_cast<fx4*>(out + OFF_SLOT);
        const long nt  = (long)BLK_SLOT * TPB;
        const long tid = (long)bid * TPB + threadIdx.x;
        #pragma unroll 4
        for (int k = 0; k < ITERS; ++k) {
            const long i = tid + (long)k * nt;
            ix4 v = __builtin_nontemporal_load(&in[i]);
            fx4 f;
            f.x = (float)v.x; f.y = (float)v.y; f.z = (float)v.z; f.w = (float)v.w;
            __builtin_nontemporal_store(f, &o[i]);
        }
    } else {
        // len or wid region: straight float4 copy
        const bool is_len = (bid < BLK_SLOT + BLK_LW);
        const fx4* in = reinterpret_cast<const fx4*>(is_len ? lens : wids);
        fx4* o = reinterpret_cast<fx4*>(out + (is_len ? OFF_LEN : OFF_WID));
        const int rb = is_len ? (bid - BLK_SLOT) : (bid - BLK_SLOT - BLK_LW);
        const long nt  = (long)BLK_LW * TPB;
        const long tid = (long)rb * TPB + threadIdx.x;
        #pragma unroll 4
        for (int k = 0; k < ITERS; ++k) {
            const long i = tid + (long)k * nt;
            fx4 v = __builtin_nontemporal_load(&in[i]);
            __builtin_nontemporal_store(v, &o[i]);
        }
    }
}

// One thread per batch element: convert+copy its barge_count row, then apply
// the sparse update logic on top of the already-copied outputs.
__global__ void update_kernel(const int*   __restrict__ sel,      // [B]
                              const float* __restrict__ bsz,      // [B,1,5]
                              const int*   __restrict__ ysel,     // [B]
                              const int*   __restrict__ bcnt,     // [B,NY]
                              const float* __restrict__ lens,     // [B,NY,MT,RR]
                              const float* __restrict__ wids,     // [B,NY,MT,RR]
                              float* __restrict__ out) {
    int b = blockIdx.x * blockDim.x + threadIdx.x;
    if (b >= B_) return;

    float* out_slot = out + OFF_SLOT;
    float* out_len  = out + OFF_LEN;
    float* out_wid  = out + OFF_WID;
    float* out_cnt  = out + OFF_CNT;

    // copy/convert this b's barge_count row
    #pragma unroll
    for (int j = 0; j < NY_; ++j)
        out_cnt[(long)b * NY_ + j] = (float)bcnt[(long)b * NY_ + j];

    const int y = ysel[b];
    const int s = bcnt[(long)b * NY_ + y];

    const long base = ((((long)b * NY_ + y) * MT_) + s) * RR_;
    const float blen = bsz[(long)b * 5 + 0];
    const float bwid = bsz[(long)b * 5 + 1];

    bool has_par_space = false;
    bool has_valid     = false;
    float maxv = -1e30f;
    int   maxi = 0;
    float total = 0.0f;

    #pragma unroll
    for (int r = 0; r < RR_; ++r) {
        const float wr = wids[base + r];
        const float lr = lens[base + r];
        const bool par = (wr <= PAR_WIDTH);
        has_par_space |= par;
        has_valid     |= (par && (wr != 0.0f));
        const float pl = par ? lr : -1.0f;
        if (pl > maxv) { maxv = pl; maxi = r; }  // first-max (strict >)
        total += lr;
    }

    const bool is_par_block = (bwid <= PAR_WIDTH);
    const bool par_alloc    = is_par_block && has_par_space;
    const bool has_existing = has_valid && par_alloc;

    const bool dir_mask  = has_existing && (maxv >= blen);
    const bool recons    = has_existing && (maxv <  blen);
    const bool allocable = (total - maxv + blen) <= MAX_LENGTH;
    const bool ra  = recons && allocable;
    const bool rna = recons && !allocable;

    if (dir_mask || ra) {
        out_slot[(base + maxi) * 2 + 1] = (float)sel[b];
        out_wid[base + maxi] = wids[base + maxi] + bwid;
        if (ra) out_len[base + maxi] = blen;
    }
    if (rna) {
        out_cnt[(long)b * NY_ + y] = (float)(s + 1);
        const int s2 = min(s + 1, MT_ - 1);
        const long base2 = ((((long)b * NY_ + y) * MT_) + s2) * RR_;
        out_slot[base2 * 2 + 0] = (float)sel[b];
        out_len[base2] = blen;
        out_wid[base2] = wids[base2] + bwid;
    }
}

extern "C" void kernel_launch(void* const* d_in, const int* in_sizes, int n_in,
                              void* d_out, int out_size, void* d_ws, size_t ws_size,
                              hipStream_t stream) {
    const int*   block_selection = (const int*)  d_in[0];
    const float* block_size      = (const float*)d_in[1];
    const int*   yard_selection  = (const int*)  d_in[2];
    const int*   barge_count     = (const int*)  d_in[3];
    const int*   barge_slot      = (const int*)  d_in[4];
    const float* lens            = (const float*)d_in[5];
    const float* wids            = (const float*)d_in[6];
    float* out = (float*)d_out;

    // One streaming launch, block-partitioned regions, branch-free bodies.
    copy_part<<<BLK_SLOT + 2 * BLK_LW, TPB, 0, stream>>>(barge_slot, lens, wids, out);

    // Sparse updates (+ barge_count convert/copy), ordered after the copy
    update_kernel<<<(B_ + 255) / 256, 256, 0, stream>>>(
        block_selection, block_size, yard_selection, barge_count, lens, wids, out);
}